// Round 11
// baseline (387.415 us; speedup 1.0000x reference)
//
#include <hip/hip_runtime.h>
#include <cstdio>
#include <cstdint>

#define HH 2048
#define WWI 2048
#define RAD 16
#define EPSF 1e-4f
#define BRA 16
#define BRB 32
#define W_OUT 94      // output cols per wave (pairs scheme: 128 loaded, 94 produced)

typedef _Float16 h16;
constexpr size_t PLN = (size_t)HH * WWI;
constexpr int ROWB = WWI * 4;          // row stride in bytes (fp32 / u32 planes)

__device__ __forceinline__ int cnt1d(int p, int n) {
    int lo = p - RAD; if (lo < 0) lo = 0;
    int hi = p + RAD; if (hi > n - 1) hi = n - 1;
    return hi - lo + 1;
}

__device__ __forceinline__ float ldf(const float* __restrict__ p, int boff) {
    return *reinterpret_cast<const float*>(reinterpret_cast<const char*>(p) + boff);
}
__device__ __forceinline__ float2 ldf2(const float* __restrict__ p, int boff) {
    return *reinterpret_cast<const float2*>(reinterpret_cast<const char*>(p) + boff);
}
__device__ __forceinline__ uint32_t ldu(const uint32_t* __restrict__ p, int boff) {
    return *reinterpret_cast<const uint32_t*>(reinterpret_cast<const char*>(p) + boff);
}
__device__ __forceinline__ void stu2(uint32_t* __restrict__ p, int boff, uint2 v) {
    *reinterpret_cast<uint2*>(reinterpret_cast<char*>(p) + boff) = v;
}
__device__ __forceinline__ void stf(float* __restrict__ p, int boff, float v) {
    *reinterpret_cast<float*>(reinterpret_cast<char*>(p) + boff) = v;
}
__device__ __forceinline__ uint32_t pk(float a, float b) {
    union { h16 h[2]; uint32_t u; } t;
    t.h[0] = (h16)a; t.h[1] = (h16)b; return t.u;
}
__device__ __forceinline__ float2 upk(uint32_t u) {
    union { uint32_t u; h16 h[2]; } t; t.u = u;
    return make_float2((float)t.h[0], (float)t.h[1]);
}

// ---- wave64 inclusive scan via DPP (proven R6/R7) ----
template<int CTRL, int RM>
__device__ __forceinline__ float dpp_add(float x) {
    int t = __builtin_amdgcn_update_dpp(0, __builtin_bit_cast(int, x), CTRL, RM, 0xf, false);
    return x + __builtin_bit_cast(float, t);
}
__device__ __forceinline__ float wscan(float x) {
    x = dpp_add<0x111, 0xf>(x);
    x = dpp_add<0x112, 0xf>(x);
    x = dpp_add<0x114, 0xf>(x);
    x = dpp_add<0x118, 0xf>(x);
    x = dpp_add<0x142, 0xa>(x);
    x = dpp_add<0x143, 0xc>(x);
    return x;
}
// NOTE: must be called with FULL exec — ds_bpermute reads from inactive lanes
// are undefined (Round-5 NaN lesson).
__device__ __forceinline__ float bperm(int byteaddr, float v) {
    return __builtin_bit_cast(float,
        __builtin_amdgcn_ds_bpermute(byteaddr, __builtin_bit_cast(int, v)));
}

template<bool ADD>
__device__ __forceinline__ void prod21(float v0, float v1, float v2,
                                       float v3, float v4, float v5, float S[21]) {
    float p[21];
    p[0] = v0; p[1] = v1; p[2] = v2; p[3] = v3; p[4] = v4; p[5] = v5;
    p[6] = v0 * v3; p[7] = v0 * v4; p[8] = v0 * v5;
    p[9] = v1 * v3; p[10] = v1 * v4; p[11] = v1 * v5;
    p[12] = v2 * v3; p[13] = v2 * v4; p[14] = v2 * v5;
    p[15] = v0 * v0; p[16] = v0 * v1; p[17] = v0 * v2;
    p[18] = v1 * v1; p[19] = v1 * v2; p[20] = v2 * v2;
#pragma unroll
    for (int c = 0; c < 21; ++c) { if constexpr (ADD) S[c] += p[c]; else S[c] -= p[c]; }
}

template<bool ADD>
__device__ __forceinline__ void acc12(const uint32_t* __restrict__ a0, const uint32_t* __restrict__ a1,
                                      const uint32_t* __restrict__ a2, const uint32_t* __restrict__ a3,
                                      const uint32_t* __restrict__ a4, const uint32_t* __restrict__ a5,
                                      int boff, bool ok, float S[12]) {
    if (!ok) return;
    const uint32_t u0 = ldu(a0, boff), u1 = ldu(a1, boff), u2 = ldu(a2, boff);
    const uint32_t u3 = ldu(a3, boff), u4 = ldu(a4, boff), u5 = ldu(a5, boff);
    const float2 f0 = upk(u0), f1 = upk(u1), f2 = upk(u2);
    const float2 f3 = upk(u3), f4 = upk(u4), f5 = upk(u5);
    if constexpr (ADD) {
        S[0] += f0.x; S[1] += f0.y; S[2] += f1.x; S[3] += f1.y;
        S[4] += f2.x; S[5] += f2.y; S[6] += f3.x; S[7] += f3.y;
        S[8] += f4.x; S[9] += f4.y; S[10] += f5.x; S[11] += f5.y;
    } else {
        S[0] -= f0.x; S[1] -= f0.y; S[2] -= f1.x; S[3] -= f1.y;
        S[4] -= f2.x; S[5] -= f2.y; S[6] -= f3.x; S[7] -= f3.y;
        S[8] -= f4.x; S[9] -= f4.y; S[10] -= f5.x; S[11] -= f5.y;
    }
}

__device__ __forceinline__ void solve_ab(const float S[21], float rN, float o[12]) {
    const float m0 = S[0] * rN, m1 = S[1] * rN, m2 = S[2] * rN;
    const float p0 = S[3] * rN, p1 = S[4] * rN, p2 = S[5] * rN;
    const float c00 = S[6] * rN - m0 * p0;
    const float c01 = S[7] * rN - m0 * p1;
    const float c02 = S[8] * rN - m0 * p2;
    const float c10 = S[9] * rN - m1 * p0;
    const float c11 = S[10] * rN - m1 * p1;
    const float c12 = S[11] * rN - m1 * p2;
    const float c20 = S[12] * rN - m2 * p0;
    const float c21 = S[13] * rN - m2 * p1;
    const float c22 = S[14] * rN - m2 * p2;
    const float vrr = S[15] * rN - m0 * m0 + EPSF;
    const float vrg = S[16] * rN - m0 * m1;
    const float vrb = S[17] * rN - m0 * m2;
    const float vgg = S[18] * rN - m1 * m1 + EPSF;
    const float vgb = S[19] * rN - m1 * m2;
    const float vbb = S[20] * rN - m2 * m2 + EPSF;
    const float det = vrr * vgg * vbb + vrg * vgb * vrb + vrb * vrg * vgb
                    - vrb * vgg * vrb - vrg * vrg * vbb - vrr * vgb * vgb;
    const float id = __builtin_amdgcn_rcpf(det);
    const float irr =  (vgg * vbb - vgb * vgb) * id;
    const float irg = -(vrg * vbb - vrb * vgb) * id;
    const float irb =  (vrg * vgb - vrb * vgg) * id;
    const float igg =  (vrr * vbb - vrb * vrb) * id;
    const float igb = -(vrr * vgb - vrb * vrg) * id;
    const float ibb =  (vrr * vgg - vrg * vrg) * id;
    const float a00 = c00 * irr + c10 * irg + c20 * irb;
    const float a01 = c01 * irr + c11 * irg + c21 * irb;
    const float a02 = c02 * irr + c12 * irg + c22 * irb;
    const float a10 = c00 * irg + c10 * igg + c20 * igb;
    const float a11 = c01 * irg + c11 * igg + c21 * igb;
    const float a12 = c02 * irg + c12 * igg + c22 * igb;
    const float a20 = c00 * irb + c10 * igb + c20 * ibb;
    const float a21 = c01 * irb + c11 * igb + c21 * ibb;
    const float a22 = c02 * irb + c12 * igb + c22 * ibb;
    o[0] = a00; o[1] = a01; o[2] = a02;
    o[3] = a10; o[4] = a11; o[5] = a12;
    o[6] = a20; o[7] = a21; o[8] = a22;
    o[9]  = p0 - a00 * m0 - a10 * m1 - a20 * m2;
    o[10] = p1 - a01 * m0 - a11 * m1 - a21 * m2;
    o[11] = p2 - a02 * m0 - a12 * m1 - a22 * m2;
}

#define LOAD6F(P, bo) { P[0] = ldf2(g0, bo); P[1] = ldf2(g1, bo); P[2] = ldf2(g2, bo); \
                        P[3] = ldf2(s0, bo); P[4] = ldf2(s1, bo); P[5] = ldf2(s2, bo); }
#define LOAD6U(P, bo) { P[0] = ldu(a0, bo); P[1] = ldu(a1, bo); P[2] = ldu(a2, bo); \
                        P[3] = ldu(a3, bo); P[4] = ldu(a4, bo); P[5] = ldu(a5, bo); }

// ---- Stage 1: pairs scheme + batched init + XCD swizzle + single-buffer prefetch ----
__global__ __launch_bounds__(128, 4) void kA(const float* __restrict__ g,
                                             const float* __restrict__ s,
                                             uint32_t* __restrict__ ab) {
    // XCD-chunked bijective swizzle: 1408 blocks = 8 * 176. Consecutive swz ids
    // share a y-band (11 x-blocks, 49-row band ~2.4MB <= 4MB XCD L2).
    const int lid = blockIdx.y * 11 + blockIdx.x;
    const int swz = (lid & 7) * 176 + (lid >> 3);
    const int bx  = swz % 11;
    const int by  = swz / 11;

    const int lane = threadIdx.x & 63;
    const int wv   = bx * 2 + (threadIdx.x >> 6);           // 0..21
    const int W0   = wv * W_OUT;
    const int X0   = W0 - 18;                               // even; loads cover [X0, X0+127]
    const int col0 = X0 + 2 * lane;
    const bool okc = (unsigned)col0 < (unsigned)WWI;        // pair-aligned (col0 even)
    const int colb = (okc ? col0 : 0) * 4;                  // safe byte offset
    const int r0   = by * BRA;
    const int aP17 = ((lane + 17) & 63) * 4;
    const int aP1  = ((lane + 1) & 63) * 4;
    const int j0   = W0 + 2 * lane;                         // = col0 + 18
    const bool outl = (lane <= 46) && (j0 < WWI);

    const float* g0 = g;         const float* g1 = g + PLN;   const float* g2 = g + 2 * PLN;
    const float* s0 = s;         const float* s1 = s + PLN;   const float* s2 = s + 2 * PLN;
    uint32_t* a0 = ab;           uint32_t* a1 = ab + PLN;     uint32_t* a2 = ab + 2 * PLN;
    uint32_t* a3 = ab + 3 * PLN; uint32_t* a4 = ab + 4 * PLN; uint32_t* a5 = ab + 5 * PLN;

    float S0[21], S1[21];
#pragma unroll
    for (int c = 0; c < 21; ++c) { S0[c] = 0.f; S1[c] = 0.f; }
    {   // band init: 4-row batches so loads overlap (registers die before main loop)
        int lo = r0 - RAD; if (lo < 0) lo = 0;
        int hi = r0 + RAD; if (hi > HH - 1) hi = HH - 1;
        int r = lo;
        if (okc) {
            int boff = lo * ROWB + col0 * 4;
            for (; r + 3 <= hi; r += 4) {
                float2 R0[6], R1[6], R2[6], R3[6];
                LOAD6F(R0, boff);
                LOAD6F(R1, boff + ROWB);
                LOAD6F(R2, boff + 2 * ROWB);
                LOAD6F(R3, boff + 3 * ROWB);
                prod21<true>(R0[0].x, R0[1].x, R0[2].x, R0[3].x, R0[4].x, R0[5].x, S0);
                prod21<true>(R0[0].y, R0[1].y, R0[2].y, R0[3].y, R0[4].y, R0[5].y, S1);
                prod21<true>(R1[0].x, R1[1].x, R1[2].x, R1[3].x, R1[4].x, R1[5].x, S0);
                prod21<true>(R1[0].y, R1[1].y, R1[2].y, R1[3].y, R1[4].y, R1[5].y, S1);
                prod21<true>(R2[0].x, R2[1].x, R2[2].x, R2[3].x, R2[4].x, R2[5].x, S0);
                prod21<true>(R2[0].y, R2[1].y, R2[2].y, R2[3].y, R2[4].y, R2[5].y, S1);
                prod21<true>(R3[0].x, R3[1].x, R3[2].x, R3[3].x, R3[4].x, R3[5].x, S0);
                prod21<true>(R3[0].y, R3[1].y, R3[2].y, R3[3].y, R3[4].y, R3[5].y, S1);
                boff += 4 * ROWB;
            }
            for (; r <= hi; ++r) {
                float2 R0[6];
                LOAD6F(R0, boff);
                prod21<true>(R0[0].x, R0[1].x, R0[2].x, R0[3].x, R0[4].x, R0[5].x, S0);
                prod21<true>(R0[0].y, R0[1].y, R0[2].y, R0[3].y, R0[4].y, R0[5].y, S1);
                boff += ROWB;
            }
        }
    }
    const float cx0 = (float)cnt1d(j0, WWI);
    const float cx1 = (float)cnt1d(j0 + 1, WWI);
    int oOff = r0 * ROWB + j0 * 4;
    for (int ii = 0; ii < BRA; ++ii) {
        const int i = r0 + ii;
        // issue this iteration's slide loads NOW (consumed after the scan)
        float2 PA[6], PB[6];
        const bool doAdv = (ii + 1 < BRA);
        if (doAdv) {
            const int boA = min(i + RAD + 1, HH - 1) * ROWB + colb;
            const int boB = max(i - RAD, 0) * ROWB + colb;
            LOAD6F(PA, boA);
            LOAD6F(PB, boB);
        }
        // scan/extract (reads S pre-update) — ~500+ cy of VALU hides the loads
        float H0[21], H1[21];
#pragma unroll
        for (int c = 0; c < 21; ++c) {
            const float PP  = wscan(S0[c] + S1[c]);   // pair-prefix, full exec
            const float ppa = bperm(aP17, PP);        // PP[L+17]
            const float s1b = bperm(aP17, S1[c]);     // S1[L+17]
            const float s0b = bperm(aP1,  S0[c]);     // S0[L+1]
            const float D = ppa - PP;
            H0[c] = D - s1b;
            H1[c] = D - s0b;
        }
        // consume prefetched rows (PA/PB die here; peak VGPR = scan end)
        if (doAdv) {
#pragma unroll
            for (int k = 0; k < 6; ++k) {   // zero OOB-lane data (cndmask)
                PA[k].x = okc ? PA[k].x : 0.f; PA[k].y = okc ? PA[k].y : 0.f;
                PB[k].x = okc ? PB[k].x : 0.f; PB[k].y = okc ? PB[k].y : 0.f;
            }
            if (i + RAD + 1 < HH) {   // wave-uniform
                prod21<true>(PA[0].x, PA[1].x, PA[2].x, PA[3].x, PA[4].x, PA[5].x, S0);
                prod21<true>(PA[0].y, PA[1].y, PA[2].y, PA[3].y, PA[4].y, PA[5].y, S1);
            }
            if (i - RAD >= 0) {       // wave-uniform
                prod21<false>(PB[0].x, PB[1].x, PB[2].x, PB[3].x, PB[4].x, PB[5].x, S0);
                prod21<false>(PB[0].y, PB[1].y, PB[2].y, PB[3].y, PB[4].y, PB[5].y, S1);
            }
        }
        // solve + store
        const float cy = (float)cnt1d(i, HH);
        float o0[12], o1[12];
        solve_ab(H0, __builtin_amdgcn_rcpf(cx0 * cy), o0);
        solve_ab(H1, __builtin_amdgcn_rcpf(cx1 * cy), o1);
        if (outl) {
            stu2(a0, oOff, make_uint2(pk(o0[0],  o0[1]),  pk(o1[0],  o1[1])));
            stu2(a1, oOff, make_uint2(pk(o0[2],  o0[3]),  pk(o1[2],  o1[3])));
            stu2(a2, oOff, make_uint2(pk(o0[4],  o0[5]),  pk(o1[4],  o1[5])));
            stu2(a3, oOff, make_uint2(pk(o0[6],  o0[7]),  pk(o1[6],  o1[7])));
            stu2(a4, oOff, make_uint2(pk(o0[8],  o0[9]),  pk(o1[8],  o1[9])));
            stu2(a5, oOff, make_uint2(pk(o0[10], o0[11]), pk(o1[10], o1[11])));
        }
        oOff += ROWB;
    }
}

// ---- Stage 2: R9 prefetch structure + XCD swizzle ----
__global__ __launch_bounds__(256) void kB(const uint32_t* __restrict__ ab,
                                          const float* __restrict__ g,
                                          float* __restrict__ outp) {
    // XCD-chunked swizzle: 1024 blocks = 8 * 128 (pow2 -> cheap).
    const int lid = blockIdx.y * 16 + blockIdx.x;
    const int swz = (lid & 7) * 128 + (lid >> 3);
    const int bx  = swz & 15;
    const int by  = swz >> 4;

    const int lane = threadIdx.x & 63;
    const int wv   = bx * 4 + (threadIdx.x >> 6);
    const int x0   = wv * 32;
    const int col  = x0 - RAD + lane;
    const bool okc = (unsigned)col < (unsigned)WWI;
    const int colb = (okc ? col : 0) * 4;
    const int r0   = by * BRB;
    const int addrA = ((lane + 16) & 63) * 4;
    const int addrB = (lane >= 17 ? lane - 17 : 0) * 4;
    const bool subok = lane >= 17;
    const bool outl  = (lane >= 16) && (lane < 48);

    const uint32_t* a0 = ab;           const uint32_t* a1 = ab + PLN;     const uint32_t* a2 = ab + 2 * PLN;
    const uint32_t* a3 = ab + 3 * PLN; const uint32_t* a4 = ab + 4 * PLN; const uint32_t* a5 = ab + 5 * PLN;
    const float* g0 = g;  const float* g1 = g + PLN;  const float* g2 = g + 2 * PLN;
    float* o0 = outp;     float* o1 = outp + PLN;     float* o2 = outp + 2 * PLN;

    float S[12];
#pragma unroll
    for (int c = 0; c < 12; ++c) S[c] = 0.f;
    {
        int lo = r0 - RAD; if (lo < 0) lo = 0;
        int hi = r0 + RAD; if (hi > HH - 1) hi = HH - 1;
        int boff = lo * ROWB + col * 4;
        for (int r = lo; r <= hi; ++r) {
            acc12<true>(a0, a1, a2, a3, a4, a5, boff, okc, S);
            boff += ROWB;
        }
    }
    const float cx = (float)cnt1d(col, WWI);
    int oOff = r0 * ROWB + col * 4;

    uint32_t UA[6], UB[6], UA2[6], UB2[6];
    {
        const int boA = min(r0 + RAD + 1, HH - 1) * ROWB + colb;
        const int boB = max(r0 - RAD, 0) * ROWB + colb;
        LOAD6U(UA, boA);
        LOAD6U(UB, boB);
    }
    for (int ii = 0; ii < BRB; ++ii) {
        const int i = r0 + ii;
        if (ii + 1 < BRB) {
            const int boA = min(i + RAD + 2, HH - 1) * ROWB + colb;
            const int boB = max(i + 1 - RAD, 0) * ROWB + colb;
            LOAD6U(UA2, boA);
            LOAD6U(UB2, boB);
        }
        float H[12];
#pragma unroll
        for (int c = 0; c < 12; ++c) {
            const float sc = wscan(S[c]);
            const float hv = bperm(addrA, sc);   // full-exec
            const float lv = bperm(addrB, sc);   // full-exec
            H[c] = hv - (subok ? lv : 0.f);
        }
        if (ii + 1 < BRB) {
#pragma unroll
            for (int k = 0; k < 6; ++k) {   // zero OOB-lane data (fp16x2 zero = 0u)
                UA[k] = okc ? UA[k] : 0u;
                UB[k] = okc ? UB[k] : 0u;
            }
            if (i + RAD + 1 < HH) {
#pragma unroll
                for (int k = 0; k < 6; ++k) {
                    const float2 f = upk(UA[k]);
                    S[2 * k] += f.x; S[2 * k + 1] += f.y;
                }
            }
            if (i - RAD >= 0) {
#pragma unroll
                for (int k = 0; k < 6; ++k) {
                    const float2 f = upk(UB[k]);
                    S[2 * k] -= f.x; S[2 * k + 1] -= f.y;
                }
            }
        }
        if (outl) {
            const float rN = __builtin_amdgcn_rcpf(cx * (float)cnt1d(i, HH));
            const float gg0 = ldf(g0, oOff), gg1 = ldf(g1, oOff), gg2 = ldf(g2, oOff);
            stf(o0, oOff, (H[0] * gg0 + H[3] * gg1 + H[6] * gg2 + H[9])  * rN);
            stf(o1, oOff, (H[1] * gg0 + H[4] * gg1 + H[7] * gg2 + H[10]) * rN);
            stf(o2, oOff, (H[2] * gg0 + H[5] * gg1 + H[8] * gg2 + H[11]) * rN);
        }
#pragma unroll
        for (int k = 0; k < 6; ++k) { UA[k] = UA2[k]; UB[k] = UB2[k]; }
        oOff += ROWB;
    }
}

extern "C" void kernel_launch(void* const* d_in, const int* in_sizes, int n_in,
                              void* d_out, int out_size, void* d_ws, size_t ws_size,
                              hipStream_t stream) {
    const float* g = (const float*)d_in[0];
    const float* s = (const float*)d_in[1];
    float* outp = (float*)d_out;
    uint32_t* ab = (uint32_t*)d_ws;

    const size_t need = 6 * PLN * sizeof(uint32_t);   // 100.7 MB
    if (ws_size < need)
        fprintf(stderr, "[gf] WARNING ws_size=%zu < need=%zu\n", ws_size, need);

    kA<<<dim3(11, HH / BRA, 1), dim3(128, 1, 1), 0, stream>>>(g, s, ab);
    kB<<<dim3(WWI / 128, HH / BRB, 1), dim3(256, 1, 1), 0, stream>>>(ab, g, outp);
}

// Round 12
// 187.285 us; speedup vs baseline: 2.0686x; 2.0686x over previous
//
#include <hip/hip_runtime.h>
#include <cstdio>
#include <cstdint>

#define HH 2048
#define WWI 2048
#define RAD 16
#define EPSF 1e-4f
#define BRA 16
#define BRB 32
#define W_OUT 94      // output cols per wave (pairs scheme: 128 loaded, 94 produced)

typedef _Float16 h16;
constexpr size_t PLN = (size_t)HH * WWI;
constexpr int ROWB = WWI * 4;          // row stride in bytes (fp32 / u32 planes)

__device__ __forceinline__ int cnt1d(int p, int n) {
    int lo = p - RAD; if (lo < 0) lo = 0;
    int hi = p + RAD; if (hi > n - 1) hi = n - 1;
    return hi - lo + 1;
}

__device__ __forceinline__ float ldf(const float* __restrict__ p, int boff) {
    return *reinterpret_cast<const float*>(reinterpret_cast<const char*>(p) + boff);
}
__device__ __forceinline__ float2 ldf2(const float* __restrict__ p, int boff) {
    return *reinterpret_cast<const float2*>(reinterpret_cast<const char*>(p) + boff);
}
__device__ __forceinline__ uint32_t ldu(const uint32_t* __restrict__ p, int boff) {
    return *reinterpret_cast<const uint32_t*>(reinterpret_cast<const char*>(p) + boff);
}
__device__ __forceinline__ void stu2(uint32_t* __restrict__ p, int boff, uint2 v) {
    *reinterpret_cast<uint2*>(reinterpret_cast<char*>(p) + boff) = v;
}
__device__ __forceinline__ void stf(float* __restrict__ p, int boff, float v) {
    *reinterpret_cast<float*>(reinterpret_cast<char*>(p) + boff) = v;
}
__device__ __forceinline__ uint32_t pk(float a, float b) {
    union { h16 h[2]; uint32_t u; } t;
    t.h[0] = (h16)a; t.h[1] = (h16)b; return t.u;
}
__device__ __forceinline__ float2 upk(uint32_t u) {
    union { uint32_t u; h16 h[2]; } t; t.u = u;
    return make_float2((float)t.h[0], (float)t.h[1]);
}

// ---- wave64 inclusive scan via DPP (proven R6/R7) ----
template<int CTRL, int RM>
__device__ __forceinline__ float dpp_add(float x) {
    int t = __builtin_amdgcn_update_dpp(0, __builtin_bit_cast(int, x), CTRL, RM, 0xf, false);
    return x + __builtin_bit_cast(float, t);
}
__device__ __forceinline__ float wscan(float x) {
    x = dpp_add<0x111, 0xf>(x);
    x = dpp_add<0x112, 0xf>(x);
    x = dpp_add<0x114, 0xf>(x);
    x = dpp_add<0x118, 0xf>(x);
    x = dpp_add<0x142, 0xa>(x);
    x = dpp_add<0x143, 0xc>(x);
    return x;
}
// NOTE: must be called with FULL exec — ds_bpermute reads from inactive lanes
// are undefined (Round-5 NaN lesson).
__device__ __forceinline__ float bperm(int byteaddr, float v) {
    return __builtin_bit_cast(float,
        __builtin_amdgcn_ds_bpermute(byteaddr, __builtin_bit_cast(int, v)));
}

template<bool ADD>
__device__ __forceinline__ void prod21(float v0, float v1, float v2,
                                       float v3, float v4, float v5, float S[21]) {
    float p[21];
    p[0] = v0; p[1] = v1; p[2] = v2; p[3] = v3; p[4] = v4; p[5] = v5;
    p[6] = v0 * v3; p[7] = v0 * v4; p[8] = v0 * v5;
    p[9] = v1 * v3; p[10] = v1 * v4; p[11] = v1 * v5;
    p[12] = v2 * v3; p[13] = v2 * v4; p[14] = v2 * v5;
    p[15] = v0 * v0; p[16] = v0 * v1; p[17] = v0 * v2;
    p[18] = v1 * v1; p[19] = v1 * v2; p[20] = v2 * v2;
#pragma unroll
    for (int c = 0; c < 21; ++c) { if constexpr (ADD) S[c] += p[c]; else S[c] -= p[c]; }
}

// single-row accumulate (exec-masked OOB skip, proven)
template<bool ADD>
__device__ __forceinline__ void acc21p(const float* __restrict__ g0, const float* __restrict__ g1,
                                       const float* __restrict__ g2, const float* __restrict__ s0,
                                       const float* __restrict__ s1, const float* __restrict__ s2,
                                       int boff, bool ok, float S0[21], float S1[21]) {
    if (!ok) return;
    const float2 a0 = ldf2(g0, boff), a1 = ldf2(g1, boff), a2 = ldf2(g2, boff);
    const float2 b0 = ldf2(s0, boff), b1 = ldf2(s1, boff), b2 = ldf2(s2, boff);
    prod21<ADD>(a0.x, a1.x, a2.x, b0.x, b1.x, b2.x, S0);
    prod21<ADD>(a0.y, a1.y, a2.y, b0.y, b1.y, b2.y, S1);
}

template<bool ADD>
__device__ __forceinline__ void acc12(const uint32_t* __restrict__ a0, const uint32_t* __restrict__ a1,
                                      const uint32_t* __restrict__ a2, const uint32_t* __restrict__ a3,
                                      const uint32_t* __restrict__ a4, const uint32_t* __restrict__ a5,
                                      int boff, bool ok, float S[12]) {
    if (!ok) return;
    const uint32_t u0 = ldu(a0, boff), u1 = ldu(a1, boff), u2 = ldu(a2, boff);
    const uint32_t u3 = ldu(a3, boff), u4 = ldu(a4, boff), u5 = ldu(a5, boff);
    const float2 f0 = upk(u0), f1 = upk(u1), f2 = upk(u2);
    const float2 f3 = upk(u3), f4 = upk(u4), f5 = upk(u5);
    if constexpr (ADD) {
        S[0] += f0.x; S[1] += f0.y; S[2] += f1.x; S[3] += f1.y;
        S[4] += f2.x; S[5] += f2.y; S[6] += f3.x; S[7] += f3.y;
        S[8] += f4.x; S[9] += f4.y; S[10] += f5.x; S[11] += f5.y;
    } else {
        S[0] -= f0.x; S[1] -= f0.y; S[2] -= f1.x; S[3] -= f1.y;
        S[4] -= f2.x; S[5] -= f2.y; S[6] -= f3.x; S[7] -= f3.y;
        S[8] -= f4.x; S[9] -= f4.y; S[10] -= f5.x; S[11] -= f5.y;
    }
}

__device__ __forceinline__ void solve_ab(const float S[21], float rN, float o[12]) {
    const float m0 = S[0] * rN, m1 = S[1] * rN, m2 = S[2] * rN;
    const float p0 = S[3] * rN, p1 = S[4] * rN, p2 = S[5] * rN;
    const float c00 = S[6] * rN - m0 * p0;
    const float c01 = S[7] * rN - m0 * p1;
    const float c02 = S[8] * rN - m0 * p2;
    const float c10 = S[9] * rN - m1 * p0;
    const float c11 = S[10] * rN - m1 * p1;
    const float c12 = S[11] * rN - m1 * p2;
    const float c20 = S[12] * rN - m2 * p0;
    const float c21 = S[13] * rN - m2 * p1;
    const float c22 = S[14] * rN - m2 * p2;
    const float vrr = S[15] * rN - m0 * m0 + EPSF;
    const float vrg = S[16] * rN - m0 * m1;
    const float vrb = S[17] * rN - m0 * m2;
    const float vgg = S[18] * rN - m1 * m1 + EPSF;
    const float vgb = S[19] * rN - m1 * m2;
    const float vbb = S[20] * rN - m2 * m2 + EPSF;
    const float det = vrr * vgg * vbb + vrg * vgb * vrb + vrb * vrg * vgb
                    - vrb * vgg * vrb - vrg * vrg * vbb - vrr * vgb * vgb;
    const float id = __builtin_amdgcn_rcpf(det);
    const float irr =  (vgg * vbb - vgb * vgb) * id;
    const float irg = -(vrg * vbb - vrb * vgb) * id;
    const float irb =  (vrg * vgb - vrb * vgg) * id;
    const float igg =  (vrr * vbb - vrb * vrb) * id;
    const float igb = -(vrr * vgb - vrb * vrg) * id;
    const float ibb =  (vrr * vgg - vrg * vrg) * id;
    const float a00 = c00 * irr + c10 * irg + c20 * irb;
    const float a01 = c01 * irr + c11 * irg + c21 * irb;
    const float a02 = c02 * irr + c12 * irg + c22 * irb;
    const float a10 = c00 * irg + c10 * igg + c20 * igb;
    const float a11 = c01 * irg + c11 * igg + c21 * igb;
    const float a12 = c02 * irg + c12 * igg + c22 * igb;
    const float a20 = c00 * irb + c10 * igb + c20 * ibb;
    const float a21 = c01 * irb + c11 * igb + c21 * ibb;
    const float a22 = c02 * irb + c12 * igb + c22 * ibb;
    o[0] = a00; o[1] = a01; o[2] = a02;
    o[3] = a10; o[4] = a11; o[5] = a12;
    o[6] = a20; o[7] = a21; o[8] = a22;
    o[9]  = p0 - a00 * m0 - a10 * m1 - a20 * m2;
    o[10] = p1 - a01 * m0 - a11 * m1 - a21 * m2;
    o[11] = p2 - a02 * m0 - a12 * m1 - a22 * m2;
}

#define LOAD6F(P, bo) { P[0] = ldf2(g0, bo); P[1] = ldf2(g1, bo); P[2] = ldf2(g2, bo); \
                        P[3] = ldf2(s0, bo); P[4] = ldf2(s1, bo); P[5] = ldf2(s2, bo); }
#define LOAD6U(P, bo) { P[0] = ldu(a0, bo); P[1] = ldu(a1, bo); P[2] = ldu(a2, bo); \
                        P[3] = ldu(a3, bo); P[4] = ldu(a4, bo); P[5] = ldu(a5, bo); }

// ---- Stage 1: exact R10 kernel + XCD-chunked swizzle (ONLY change) ----
__global__ __launch_bounds__(128, 3) void kA(const float* __restrict__ g,
                                             const float* __restrict__ s,
                                             uint32_t* __restrict__ ab) {
    // XCD-chunked bijective swizzle: 1408 blocks = 8 * 176. Consecutive swz ids
    // within an XCD share y-bands (11 x-blocks per 49-row band ~2.4MB <= 4MB L2).
    const int lid = blockIdx.y * 11 + blockIdx.x;
    const int swz = (lid & 7) * 176 + (lid >> 3);
    const int bx  = swz % 11;
    const int by  = swz / 11;

    const int lane = threadIdx.x & 63;
    const int wv   = bx * 2 + (threadIdx.x >> 6);           // 0..21
    const int W0   = wv * W_OUT;
    const int X0   = W0 - 18;                               // even; loads cover [X0, X0+127]
    const int col0 = X0 + 2 * lane;
    const bool okc = (unsigned)col0 < (unsigned)WWI;        // pair-aligned (col0 even)
    const int r0   = by * BRA;
    const int aP17 = ((lane + 17) & 63) * 4;
    const int aP1  = ((lane + 1) & 63) * 4;
    const int j0   = W0 + 2 * lane;                         // = col0 + 18
    const bool outl = (lane <= 46) && (j0 < WWI);

    const float* g0 = g;         const float* g1 = g + PLN;   const float* g2 = g + 2 * PLN;
    const float* s0 = s;         const float* s1 = s + PLN;   const float* s2 = s + 2 * PLN;
    uint32_t* a0 = ab;           uint32_t* a1 = ab + PLN;     uint32_t* a2 = ab + 2 * PLN;
    uint32_t* a3 = ab + 3 * PLN; uint32_t* a4 = ab + 4 * PLN; uint32_t* a5 = ab + 5 * PLN;

    float S0[21], S1[21];
#pragma unroll
    for (int c = 0; c < 21; ++c) { S0[c] = 0.f; S1[c] = 0.f; }
    {   // band init: 4-row batches so loads overlap (registers die before main loop)
        int lo = r0 - RAD; if (lo < 0) lo = 0;
        int hi = r0 + RAD; if (hi > HH - 1) hi = HH - 1;
        int r = lo;
        if (okc) {
            int boff = lo * ROWB + col0 * 4;
            for (; r + 3 <= hi; r += 4) {
                float2 R0[6], R1[6], R2[6], R3[6];
                LOAD6F(R0, boff);
                LOAD6F(R1, boff + ROWB);
                LOAD6F(R2, boff + 2 * ROWB);
                LOAD6F(R3, boff + 3 * ROWB);
                prod21<true>(R0[0].x, R0[1].x, R0[2].x, R0[3].x, R0[4].x, R0[5].x, S0);
                prod21<true>(R0[0].y, R0[1].y, R0[2].y, R0[3].y, R0[4].y, R0[5].y, S1);
                prod21<true>(R1[0].x, R1[1].x, R1[2].x, R1[3].x, R1[4].x, R1[5].x, S0);
                prod21<true>(R1[0].y, R1[1].y, R1[2].y, R1[3].y, R1[4].y, R1[5].y, S1);
                prod21<true>(R2[0].x, R2[1].x, R2[2].x, R2[3].x, R2[4].x, R2[5].x, S0);
                prod21<true>(R2[0].y, R2[1].y, R2[2].y, R2[3].y, R2[4].y, R2[5].y, S1);
                prod21<true>(R3[0].x, R3[1].x, R3[2].x, R3[3].x, R3[4].x, R3[5].x, S0);
                prod21<true>(R3[0].y, R3[1].y, R3[2].y, R3[3].y, R3[4].y, R3[5].y, S1);
                boff += 4 * ROWB;
            }
            for (; r <= hi; ++r) {
                float2 R0[6];
                LOAD6F(R0, boff);
                prod21<true>(R0[0].x, R0[1].x, R0[2].x, R0[3].x, R0[4].x, R0[5].x, S0);
                prod21<true>(R0[0].y, R0[1].y, R0[2].y, R0[3].y, R0[4].y, R0[5].y, S1);
                boff += ROWB;
            }
        }
    }
    const float cx0 = (float)cnt1d(j0, WWI);
    const float cx1 = (float)cnt1d(j0 + 1, WWI);
    int raOff = (r0 + RAD + 1) * ROWB + col0 * 4;
    int rsOff = (r0 - RAD) * ROWB + col0 * 4;
    int oOff  = r0 * ROWB + j0 * 4;
    for (int ii = 0; ii < BRA; ++ii) {
        const int i = r0 + ii;
        float H0[21], H1[21];
#pragma unroll
        for (int c = 0; c < 21; ++c) {
            const float PP  = wscan(S0[c] + S1[c]);   // pair-prefix, full exec
            const float ppa = bperm(aP17, PP);        // PP[L+17]
            const float s1b = bperm(aP17, S1[c]);     // S1[L+17]
            const float s0b = bperm(aP1,  S0[c]);     // S0[L+1]
            const float D = ppa - PP;
            H0[c] = D - s1b;
            H1[c] = D - s0b;
        }
        const float cy = (float)cnt1d(i, HH);
        float o0[12], o1[12];
        solve_ab(H0, __builtin_amdgcn_rcpf(cx0 * cy), o0);
        solve_ab(H1, __builtin_amdgcn_rcpf(cx1 * cy), o1);
        if (outl) {
            stu2(a0, oOff, make_uint2(pk(o0[0],  o0[1]),  pk(o1[0],  o1[1])));
            stu2(a1, oOff, make_uint2(pk(o0[2],  o0[3]),  pk(o1[2],  o1[3])));
            stu2(a2, oOff, make_uint2(pk(o0[4],  o0[5]),  pk(o1[4],  o1[5])));
            stu2(a3, oOff, make_uint2(pk(o0[6],  o0[7]),  pk(o1[6],  o1[7])));
            stu2(a4, oOff, make_uint2(pk(o0[8],  o0[9]),  pk(o1[8],  o1[9])));
            stu2(a5, oOff, make_uint2(pk(o0[10], o0[11]), pk(o1[10], o1[11])));
        }
        if (ii + 1 < BRA) {   // peel: last iteration's slide advance is dead work
            if (i + RAD + 1 < HH) acc21p<true >(g0, g1, g2, s0, s1, s2, raOff, okc, S0, S1);
            if (i - RAD >= 0)     acc21p<false>(g0, g1, g2, s0, s1, s2, rsOff, okc, S0, S1);
        }
        raOff += ROWB; rsOff += ROWB; oOff += ROWB;
    }
}

// ---- Stage 2: exact R10 kernel + XCD-chunked swizzle (ONLY change) ----
__global__ __launch_bounds__(256) void kB(const uint32_t* __restrict__ ab,
                                          const float* __restrict__ g,
                                          float* __restrict__ outp) {
    // XCD-chunked swizzle: 1024 blocks = 8 * 128 (pow2 -> cheap).
    const int lid = blockIdx.y * 16 + blockIdx.x;
    const int swz = (lid & 7) * 128 + (lid >> 3);
    const int bx  = swz & 15;
    const int by  = swz >> 4;

    const int lane = threadIdx.x & 63;
    const int wv   = bx * 4 + (threadIdx.x >> 6);
    const int x0   = wv * 32;
    const int col  = x0 - RAD + lane;
    const bool okc = (unsigned)col < (unsigned)WWI;
    const int colb = (okc ? col : 0) * 4;
    const int r0   = by * BRB;
    const int addrA = ((lane + 16) & 63) * 4;
    const int addrB = (lane >= 17 ? lane - 17 : 0) * 4;
    const bool subok = lane >= 17;
    const bool outl  = (lane >= 16) && (lane < 48);

    const uint32_t* a0 = ab;           const uint32_t* a1 = ab + PLN;     const uint32_t* a2 = ab + 2 * PLN;
    const uint32_t* a3 = ab + 3 * PLN; const uint32_t* a4 = ab + 4 * PLN; const uint32_t* a5 = ab + 5 * PLN;
    const float* g0 = g;  const float* g1 = g + PLN;  const float* g2 = g + 2 * PLN;
    float* o0 = outp;     float* o1 = outp + PLN;     float* o2 = outp + 2 * PLN;

    float S[12];
#pragma unroll
    for (int c = 0; c < 12; ++c) S[c] = 0.f;
    {
        int lo = r0 - RAD; if (lo < 0) lo = 0;
        int hi = r0 + RAD; if (hi > HH - 1) hi = HH - 1;
        int boff = lo * ROWB + col * 4;
        for (int r = lo; r <= hi; ++r) {
            acc12<true>(a0, a1, a2, a3, a4, a5, boff, okc, S);
            boff += ROWB;
        }
    }
    const float cx = (float)cnt1d(col, WWI);
    int oOff = r0 * ROWB + col * 4;

    uint32_t UA[6], UB[6], UA2[6], UB2[6];
    {
        const int boA = min(r0 + RAD + 1, HH - 1) * ROWB + colb;
        const int boB = max(r0 - RAD, 0) * ROWB + colb;
        LOAD6U(UA, boA);
        LOAD6U(UB, boB);
    }
    for (int ii = 0; ii < BRB; ++ii) {
        const int i = r0 + ii;
        if (ii + 1 < BRB) {
            const int boA = min(i + RAD + 2, HH - 1) * ROWB + colb;
            const int boB = max(i + 1 - RAD, 0) * ROWB + colb;
            LOAD6U(UA2, boA);
            LOAD6U(UB2, boB);
        }
        float H[12];
#pragma unroll
        for (int c = 0; c < 12; ++c) {
            const float sc = wscan(S[c]);
            const float hv = bperm(addrA, sc);   // full-exec
            const float lv = bperm(addrB, sc);   // full-exec
            H[c] = hv - (subok ? lv : 0.f);
        }
        if (ii + 1 < BRB) {
#pragma unroll
            for (int k = 0; k < 6; ++k) {   // zero OOB-lane data (fp16x2 zero = 0u)
                UA[k] = okc ? UA[k] : 0u;
                UB[k] = okc ? UB[k] : 0u;
            }
            if (i + RAD + 1 < HH) {
#pragma unroll
                for (int k = 0; k < 6; ++k) {
                    const float2 f = upk(UA[k]);
                    S[2 * k] += f.x; S[2 * k + 1] += f.y;
                }
            }
            if (i - RAD >= 0) {
#pragma unroll
                for (int k = 0; k < 6; ++k) {
                    const float2 f = upk(UB[k]);
                    S[2 * k] -= f.x; S[2 * k + 1] -= f.y;
                }
            }
        }
        if (outl) {
            const float rN = __builtin_amdgcn_rcpf(cx * (float)cnt1d(i, HH));
            const float gg0 = ldf(g0, oOff), gg1 = ldf(g1, oOff), gg2 = ldf(g2, oOff);
            stf(o0, oOff, (H[0] * gg0 + H[3] * gg1 + H[6] * gg2 + H[9])  * rN);
            stf(o1, oOff, (H[1] * gg0 + H[4] * gg1 + H[7] * gg2 + H[10]) * rN);
            stf(o2, oOff, (H[2] * gg0 + H[5] * gg1 + H[8] * gg2 + H[11]) * rN);
        }
#pragma unroll
        for (int k = 0; k < 6; ++k) { UA[k] = UA2[k]; UB[k] = UB2[k]; }
        oOff += ROWB;
    }
}

extern "C" void kernel_launch(void* const* d_in, const int* in_sizes, int n_in,
                              void* d_out, int out_size, void* d_ws, size_t ws_size,
                              hipStream_t stream) {
    const float* g = (const float*)d_in[0];
    const float* s = (const float*)d_in[1];
    float* outp = (float*)d_out;
    uint32_t* ab = (uint32_t*)d_ws;

    const size_t need = 6 * PLN * sizeof(uint32_t);   // 100.7 MB
    if (ws_size < need)
        fprintf(stderr, "[gf] WARNING ws_size=%zu < need=%zu\n", ws_size, need);

    kA<<<dim3(11, HH / BRA, 1), dim3(128, 1, 1), 0, stream>>>(g, s, ab);
    kB<<<dim3(WWI / 128, HH / BRB, 1), dim3(256, 1, 1), 0, stream>>>(ab, g, outp);
}

// Round 13
// 176.180 us; speedup vs baseline: 2.1990x; 1.0630x over previous
//
#include <hip/hip_runtime.h>
#include <cstdio>
#include <cstdint>

#define HH 2048
#define WWI 2048
#define RAD 16
#define EPSF 1e-4f
#define BRA 16
#define BRB 32
#define W_OUT 94      // output cols per wave (pairs scheme: 128 loaded, 94 produced)

typedef _Float16 h16;
constexpr size_t PLN = (size_t)HH * WWI;
constexpr int ROWB = WWI * 4;          // row stride in bytes (fp32 / u32 planes)

__device__ __forceinline__ int cnt1d(int p, int n) {
    int lo = p - RAD; if (lo < 0) lo = 0;
    int hi = p + RAD; if (hi > n - 1) hi = n - 1;
    return hi - lo + 1;
}

__device__ __forceinline__ float ldf(const float* __restrict__ p, int boff) {
    return *reinterpret_cast<const float*>(reinterpret_cast<const char*>(p) + boff);
}
__device__ __forceinline__ float2 ldf2(const float* __restrict__ p, int boff) {
    return *reinterpret_cast<const float2*>(reinterpret_cast<const char*>(p) + boff);
}
__device__ __forceinline__ uint32_t ldu(const uint32_t* __restrict__ p, int boff) {
    return *reinterpret_cast<const uint32_t*>(reinterpret_cast<const char*>(p) + boff);
}
__device__ __forceinline__ void stu2(uint32_t* __restrict__ p, int boff, uint2 v) {
    *reinterpret_cast<uint2*>(reinterpret_cast<char*>(p) + boff) = v;
}
__device__ __forceinline__ void stf(float* __restrict__ p, int boff, float v) {
    *reinterpret_cast<float*>(reinterpret_cast<char*>(p) + boff) = v;
}
__device__ __forceinline__ uint32_t pk(float a, float b) {
    union { h16 h[2]; uint32_t u; } t;
    t.h[0] = (h16)a; t.h[1] = (h16)b; return t.u;
}
__device__ __forceinline__ float2 upk(uint32_t u) {
    union { uint32_t u; h16 h[2]; } t; t.u = u;
    return make_float2((float)t.h[0], (float)t.h[1]);
}

// ---- wave64 inclusive scan via DPP (proven R6/R7) ----
template<int CTRL, int RM>
__device__ __forceinline__ float dpp_add(float x) {
    int t = __builtin_amdgcn_update_dpp(0, __builtin_bit_cast(int, x), CTRL, RM, 0xf, false);
    return x + __builtin_bit_cast(float, t);
}
__device__ __forceinline__ float wscan(float x) {
    x = dpp_add<0x111, 0xf>(x);
    x = dpp_add<0x112, 0xf>(x);
    x = dpp_add<0x114, 0xf>(x);
    x = dpp_add<0x118, 0xf>(x);
    x = dpp_add<0x142, 0xa>(x);
    x = dpp_add<0x143, 0xc>(x);
    return x;
}
// NOTE: must be called with FULL exec — ds_bpermute reads from inactive lanes
// are undefined (Round-5 NaN lesson).
__device__ __forceinline__ float bperm(int byteaddr, float v) {
    return __builtin_bit_cast(float,
        __builtin_amdgcn_ds_bpermute(byteaddr, __builtin_bit_cast(int, v)));
}

template<bool ADD>
__device__ __forceinline__ void prod21(float v0, float v1, float v2,
                                       float v3, float v4, float v5, float S[21]) {
    float p[21];
    p[0] = v0; p[1] = v1; p[2] = v2; p[3] = v3; p[4] = v4; p[5] = v5;
    p[6] = v0 * v3; p[7] = v0 * v4; p[8] = v0 * v5;
    p[9] = v1 * v3; p[10] = v1 * v4; p[11] = v1 * v5;
    p[12] = v2 * v3; p[13] = v2 * v4; p[14] = v2 * v5;
    p[15] = v0 * v0; p[16] = v0 * v1; p[17] = v0 * v2;
    p[18] = v1 * v1; p[19] = v1 * v2; p[20] = v2 * v2;
#pragma unroll
    for (int c = 0; c < 21; ++c) { if constexpr (ADD) S[c] += p[c]; else S[c] -= p[c]; }
}

template<bool ADD>
__device__ __forceinline__ void acc12(const uint32_t* __restrict__ a0, const uint32_t* __restrict__ a1,
                                      const uint32_t* __restrict__ a2, const uint32_t* __restrict__ a3,
                                      const uint32_t* __restrict__ a4, const uint32_t* __restrict__ a5,
                                      int boff, bool ok, float S[12]) {
    if (!ok) return;
    const uint32_t u0 = ldu(a0, boff), u1 = ldu(a1, boff), u2 = ldu(a2, boff);
    const uint32_t u3 = ldu(a3, boff), u4 = ldu(a4, boff), u5 = ldu(a5, boff);
    const float2 f0 = upk(u0), f1 = upk(u1), f2 = upk(u2);
    const float2 f3 = upk(u3), f4 = upk(u4), f5 = upk(u5);
    if constexpr (ADD) {
        S[0] += f0.x; S[1] += f0.y; S[2] += f1.x; S[3] += f1.y;
        S[4] += f2.x; S[5] += f2.y; S[6] += f3.x; S[7] += f3.y;
        S[8] += f4.x; S[9] += f4.y; S[10] += f5.x; S[11] += f5.y;
    } else {
        S[0] -= f0.x; S[1] -= f0.y; S[2] -= f1.x; S[3] -= f1.y;
        S[4] -= f2.x; S[5] -= f2.y; S[6] -= f3.x; S[7] -= f3.y;
        S[8] -= f4.x; S[9] -= f4.y; S[10] -= f5.x; S[11] -= f5.y;
    }
}

__device__ __forceinline__ void solve_ab(const float S[21], float rN, float o[12]) {
    const float m0 = S[0] * rN, m1 = S[1] * rN, m2 = S[2] * rN;
    const float p0 = S[3] * rN, p1 = S[4] * rN, p2 = S[5] * rN;
    const float c00 = S[6] * rN - m0 * p0;
    const float c01 = S[7] * rN - m0 * p1;
    const float c02 = S[8] * rN - m0 * p2;
    const float c10 = S[9] * rN - m1 * p0;
    const float c11 = S[10] * rN - m1 * p1;
    const float c12 = S[11] * rN - m1 * p2;
    const float c20 = S[12] * rN - m2 * p0;
    const float c21 = S[13] * rN - m2 * p1;
    const float c22 = S[14] * rN - m2 * p2;
    const float vrr = S[15] * rN - m0 * m0 + EPSF;
    const float vrg = S[16] * rN - m0 * m1;
    const float vrb = S[17] * rN - m0 * m2;
    const float vgg = S[18] * rN - m1 * m1 + EPSF;
    const float vgb = S[19] * rN - m1 * m2;
    const float vbb = S[20] * rN - m2 * m2 + EPSF;
    const float det = vrr * vgg * vbb + vrg * vgb * vrb + vrb * vrg * vgb
                    - vrb * vgg * vrb - vrg * vrg * vbb - vrr * vgb * vgb;
    const float id = __builtin_amdgcn_rcpf(det);
    const float irr =  (vgg * vbb - vgb * vgb) * id;
    const float irg = -(vrg * vbb - vrb * vgb) * id;
    const float irb =  (vrg * vgb - vrb * vgg) * id;
    const float igg =  (vrr * vbb - vrb * vrb) * id;
    const float igb = -(vrr * vgb - vrb * vrg) * id;
    const float ibb =  (vrr * vgg - vrg * vrg) * id;
    const float a00 = c00 * irr + c10 * irg + c20 * irb;
    const float a01 = c01 * irr + c11 * irg + c21 * irb;
    const float a02 = c02 * irr + c12 * irg + c22 * irb;
    const float a10 = c00 * irg + c10 * igg + c20 * igb;
    const float a11 = c01 * irg + c11 * igg + c21 * igb;
    const float a12 = c02 * irg + c12 * igg + c22 * igb;
    const float a20 = c00 * irb + c10 * igb + c20 * ibb;
    const float a21 = c01 * irb + c11 * igb + c21 * ibb;
    const float a22 = c02 * irb + c12 * igb + c22 * ibb;
    o[0] = a00; o[1] = a01; o[2] = a02;
    o[3] = a10; o[4] = a11; o[5] = a12;
    o[6] = a20; o[7] = a21; o[8] = a22;
    o[9]  = p0 - a00 * m0 - a10 * m1 - a20 * m2;
    o[10] = p1 - a01 * m0 - a11 * m1 - a21 * m2;
    o[11] = p2 - a02 * m0 - a12 * m1 - a22 * m2;
}

#define LOAD6F(P, bo) { P[0] = ldf2(g0, bo); P[1] = ldf2(g1, bo); P[2] = ldf2(g2, bo); \
                        P[3] = ldf2(s0, bo); P[4] = ldf2(s1, bo); P[5] = ldf2(s2, bo); }
#define LOAD6U(P, bo) { P[0] = ldu(a0, bo); P[1] = ldu(a1, bo); P[2] = ldu(a2, bo); \
                        P[3] = ldu(a3, bo); P[4] = ldu(a4, bo); P[5] = ldu(a5, bo); }

// ---- Stage 1: R12 + intra-iteration prefetch (issue loads before scan) ----
// launch_bounds(128,3) UNCHANGED — R11's regression was the (128,4) pin, not the prefetch.
__global__ __launch_bounds__(128, 3) void kA(const float* __restrict__ g,
                                             const float* __restrict__ s,
                                             uint32_t* __restrict__ ab) {
    // XCD-chunked bijective swizzle (proven R12: FETCH -32%).
    const int lid = blockIdx.y * 11 + blockIdx.x;
    const int swz = (lid & 7) * 176 + (lid >> 3);
    const int bx  = swz % 11;
    const int by  = swz / 11;

    const int lane = threadIdx.x & 63;
    const int wv   = bx * 2 + (threadIdx.x >> 6);           // 0..21
    const int W0   = wv * W_OUT;
    const int X0   = W0 - 18;                               // even; loads cover [X0, X0+127]
    const int col0 = X0 + 2 * lane;
    const bool okc = (unsigned)col0 < (unsigned)WWI;        // pair-aligned (col0 even)
    const int colb = (okc ? col0 : 0) * 4;                  // safe byte offset for prefetch
    const int r0   = by * BRA;
    const int aP17 = ((lane + 17) & 63) * 4;
    const int aP1  = ((lane + 1) & 63) * 4;
    const int j0   = W0 + 2 * lane;                         // = col0 + 18
    const bool outl = (lane <= 46) && (j0 < WWI);

    const float* g0 = g;         const float* g1 = g + PLN;   const float* g2 = g + 2 * PLN;
    const float* s0 = s;         const float* s1 = s + PLN;   const float* s2 = s + 2 * PLN;
    uint32_t* a0 = ab;           uint32_t* a1 = ab + PLN;     uint32_t* a2 = ab + 2 * PLN;
    uint32_t* a3 = ab + 3 * PLN; uint32_t* a4 = ab + 4 * PLN; uint32_t* a5 = ab + 5 * PLN;

    float S0[21], S1[21];
#pragma unroll
    for (int c = 0; c < 21; ++c) { S0[c] = 0.f; S1[c] = 0.f; }
    {   // band init: 4-row batches so loads overlap (registers die before main loop)
        int lo = r0 - RAD; if (lo < 0) lo = 0;
        int hi = r0 + RAD; if (hi > HH - 1) hi = HH - 1;
        int r = lo;
        if (okc) {
            int boff = lo * ROWB + col0 * 4;
            for (; r + 3 <= hi; r += 4) {
                float2 R0[6], R1[6], R2[6], R3[6];
                LOAD6F(R0, boff);
                LOAD6F(R1, boff + ROWB);
                LOAD6F(R2, boff + 2 * ROWB);
                LOAD6F(R3, boff + 3 * ROWB);
                prod21<true>(R0[0].x, R0[1].x, R0[2].x, R0[3].x, R0[4].x, R0[5].x, S0);
                prod21<true>(R0[0].y, R0[1].y, R0[2].y, R0[3].y, R0[4].y, R0[5].y, S1);
                prod21<true>(R1[0].x, R1[1].x, R1[2].x, R1[3].x, R1[4].x, R1[5].x, S0);
                prod21<true>(R1[0].y, R1[1].y, R1[2].y, R1[3].y, R1[4].y, R1[5].y, S1);
                prod21<true>(R2[0].x, R2[1].x, R2[2].x, R2[3].x, R2[4].x, R2[5].x, S0);
                prod21<true>(R2[0].y, R2[1].y, R2[2].y, R2[3].y, R2[4].y, R2[5].y, S1);
                prod21<true>(R3[0].x, R3[1].x, R3[2].x, R3[3].x, R3[4].x, R3[5].x, S0);
                prod21<true>(R3[0].y, R3[1].y, R3[2].y, R3[3].y, R3[4].y, R3[5].y, S1);
                boff += 4 * ROWB;
            }
            for (; r <= hi; ++r) {
                float2 R0[6];
                LOAD6F(R0, boff);
                prod21<true>(R0[0].x, R0[1].x, R0[2].x, R0[3].x, R0[4].x, R0[5].x, S0);
                prod21<true>(R0[0].y, R0[1].y, R0[2].y, R0[3].y, R0[4].y, R0[5].y, S1);
                boff += ROWB;
            }
        }
    }
    const float cx0 = (float)cnt1d(j0, WWI);
    const float cx1 = (float)cnt1d(j0 + 1, WWI);
    int oOff = r0 * ROWB + j0 * 4;
    for (int ii = 0; ii < BRA; ++ii) {
        const int i = r0 + ii;
        // issue this iteration's slide loads NOW; the 21-channel scan (~250 VALU)
        // runs between issue and consume -> latency hidden. +24 transient VGPRs.
        float2 PA[6], PB[6];
        const bool doAdv = (ii + 1 < BRA);
        if (doAdv) {
            const int boA = min(i + RAD + 1, HH - 1) * ROWB + colb;
            const int boB = max(i - RAD, 0) * ROWB + colb;
            LOAD6F(PA, boA);
            LOAD6F(PB, boB);
        }
        // scan/extract (reads S pre-update)
        float H0[21], H1[21];
#pragma unroll
        for (int c = 0; c < 21; ++c) {
            const float PP  = wscan(S0[c] + S1[c]);   // pair-prefix, full exec
            const float ppa = bperm(aP17, PP);        // PP[L+17]
            const float s1b = bperm(aP17, S1[c]);     // S1[L+17]
            const float s0b = bperm(aP1,  S0[c]);     // S0[L+1]
            const float D = ppa - PP;
            H0[c] = D - s1b;
            H1[c] = D - s0b;
        }
        // consume prefetched rows (PA/PB die here)
        if (doAdv) {
#pragma unroll
            for (int k = 0; k < 6; ++k) {   // zero OOB-lane data (cndmask)
                PA[k].x = okc ? PA[k].x : 0.f; PA[k].y = okc ? PA[k].y : 0.f;
                PB[k].x = okc ? PB[k].x : 0.f; PB[k].y = okc ? PB[k].y : 0.f;
            }
            if (i + RAD + 1 < HH) {   // wave-uniform
                prod21<true>(PA[0].x, PA[1].x, PA[2].x, PA[3].x, PA[4].x, PA[5].x, S0);
                prod21<true>(PA[0].y, PA[1].y, PA[2].y, PA[3].y, PA[4].y, PA[5].y, S1);
            }
            if (i - RAD >= 0) {       // wave-uniform
                prod21<false>(PB[0].x, PB[1].x, PB[2].x, PB[3].x, PB[4].x, PB[5].x, S0);
                prod21<false>(PB[0].y, PB[1].y, PB[2].y, PB[3].y, PB[4].y, PB[5].y, S1);
            }
        }
        // solve + store
        const float cy = (float)cnt1d(i, HH);
        float o0[12], o1[12];
        solve_ab(H0, __builtin_amdgcn_rcpf(cx0 * cy), o0);
        solve_ab(H1, __builtin_amdgcn_rcpf(cx1 * cy), o1);
        if (outl) {
            stu2(a0, oOff, make_uint2(pk(o0[0],  o0[1]),  pk(o1[0],  o1[1])));
            stu2(a1, oOff, make_uint2(pk(o0[2],  o0[3]),  pk(o1[2],  o1[3])));
            stu2(a2, oOff, make_uint2(pk(o0[4],  o0[5]),  pk(o1[4],  o1[5])));
            stu2(a3, oOff, make_uint2(pk(o0[6],  o0[7]),  pk(o1[6],  o1[7])));
            stu2(a4, oOff, make_uint2(pk(o0[8],  o0[9]),  pk(o1[8],  o1[9])));
            stu2(a5, oOff, make_uint2(pk(o0[10], o0[11]), pk(o1[10], o1[11])));
        }
        oOff += ROWB;
    }
}

// ---- Stage 2: exact R12 kernel (proven; untouched) ----
__global__ __launch_bounds__(256) void kB(const uint32_t* __restrict__ ab,
                                          const float* __restrict__ g,
                                          float* __restrict__ outp) {
    const int lid = blockIdx.y * 16 + blockIdx.x;
    const int swz = (lid & 7) * 128 + (lid >> 3);
    const int bx  = swz & 15;
    const int by  = swz >> 4;

    const int lane = threadIdx.x & 63;
    const int wv   = bx * 4 + (threadIdx.x >> 6);
    const int x0   = wv * 32;
    const int col  = x0 - RAD + lane;
    const bool okc = (unsigned)col < (unsigned)WWI;
    const int colb = (okc ? col : 0) * 4;
    const int r0   = by * BRB;
    const int addrA = ((lane + 16) & 63) * 4;
    const int addrB = (lane >= 17 ? lane - 17 : 0) * 4;
    const bool subok = lane >= 17;
    const bool outl  = (lane >= 16) && (lane < 48);

    const uint32_t* a0 = ab;           const uint32_t* a1 = ab + PLN;     const uint32_t* a2 = ab + 2 * PLN;
    const uint32_t* a3 = ab + 3 * PLN; const uint32_t* a4 = ab + 4 * PLN; const uint32_t* a5 = ab + 5 * PLN;
    const float* g0 = g;  const float* g1 = g + PLN;  const float* g2 = g + 2 * PLN;
    float* o0 = outp;     float* o1 = outp + PLN;     float* o2 = outp + 2 * PLN;

    float S[12];
#pragma unroll
    for (int c = 0; c < 12; ++c) S[c] = 0.f;
    {
        int lo = r0 - RAD; if (lo < 0) lo = 0;
        int hi = r0 + RAD; if (hi > HH - 1) hi = HH - 1;
        int boff = lo * ROWB + col * 4;
        for (int r = lo; r <= hi; ++r) {
            acc12<true>(a0, a1, a2, a3, a4, a5, boff, okc, S);
            boff += ROWB;
        }
    }
    const float cx = (float)cnt1d(col, WWI);
    int oOff = r0 * ROWB + col * 4;

    uint32_t UA[6], UB[6], UA2[6], UB2[6];
    {
        const int boA = min(r0 + RAD + 1, HH - 1) * ROWB + colb;
        const int boB = max(r0 - RAD, 0) * ROWB + colb;
        LOAD6U(UA, boA);
        LOAD6U(UB, boB);
    }
    for (int ii = 0; ii < BRB; ++ii) {
        const int i = r0 + ii;
        if (ii + 1 < BRB) {
            const int boA = min(i + RAD + 2, HH - 1) * ROWB + colb;
            const int boB = max(i + 1 - RAD, 0) * ROWB + colb;
            LOAD6U(UA2, boA);
            LOAD6U(UB2, boB);
        }
        float H[12];
#pragma unroll
        for (int c = 0; c < 12; ++c) {
            const float sc = wscan(S[c]);
            const float hv = bperm(addrA, sc);   // full-exec
            const float lv = bperm(addrB, sc);   // full-exec
            H[c] = hv - (subok ? lv : 0.f);
        }
        if (ii + 1 < BRB) {
#pragma unroll
            for (int k = 0; k < 6; ++k) {   // zero OOB-lane data (fp16x2 zero = 0u)
                UA[k] = okc ? UA[k] : 0u;
                UB[k] = okc ? UB[k] : 0u;
            }
            if (i + RAD + 1 < HH) {
#pragma unroll
                for (int k = 0; k < 6; ++k) {
                    const float2 f = upk(UA[k]);
                    S[2 * k] += f.x; S[2 * k + 1] += f.y;
                }
            }
            if (i - RAD >= 0) {
#pragma unroll
                for (int k = 0; k < 6; ++k) {
                    const float2 f = upk(UB[k]);
                    S[2 * k] -= f.x; S[2 * k + 1] -= f.y;
                }
            }
        }
        if (outl) {
            const float rN = __builtin_amdgcn_rcpf(cx * (float)cnt1d(i, HH));
            const float gg0 = ldf(g0, oOff), gg1 = ldf(g1, oOff), gg2 = ldf(g2, oOff);
            stf(o0, oOff, (H[0] * gg0 + H[3] * gg1 + H[6] * gg2 + H[9])  * rN);
            stf(o1, oOff, (H[1] * gg0 + H[4] * gg1 + H[7] * gg2 + H[10]) * rN);
            stf(o2, oOff, (H[2] * gg0 + H[5] * gg1 + H[8] * gg2 + H[11]) * rN);
        }
#pragma unroll
        for (int k = 0; k < 6; ++k) { UA[k] = UA2[k]; UB[k] = UB2[k]; }
        oOff += ROWB;
    }
}

extern "C" void kernel_launch(void* const* d_in, const int* in_sizes, int n_in,
                              void* d_out, int out_size, void* d_ws, size_t ws_size,
                              hipStream_t stream) {
    const float* g = (const float*)d_in[0];
    const float* s = (const float*)d_in[1];
    float* outp = (float*)d_out;
    uint32_t* ab = (uint32_t*)d_ws;

    const size_t need = 6 * PLN * sizeof(uint32_t);   // 100.7 MB
    if (ws_size < need)
        fprintf(stderr, "[gf] WARNING ws_size=%zu < need=%zu\n", ws_size, need);

    kA<<<dim3(11, HH / BRA, 1), dim3(128, 1, 1), 0, stream>>>(g, s, ab);
    kB<<<dim3(WWI / 128, HH / BRB, 1), dim3(256, 1, 1), 0, stream>>>(ab, g, outp);
}